// Round 1
// baseline (108.479 us; speedup 1.0000x reference)
//
#include <hip/hip_runtime.h>
#include <math.h>

#define VOCAB 50257
#define BSZ   64
#define BEAM  8
#define NG    4     // NUM_GROUPS
#define MB    2     // beams per group
#define KC    2     // candidates per group (CAND_MULT * mb)
#define TLEN  128   // scores T dim
#define NGRAM 2
#define TPB   1024

__device__ __forceinline__ bool better(float v1, int i1, float v2, int i2) {
    return (v1 > v2) || (v1 == v2 && i1 < i2);
}

struct Top2 { float v1, v2; int i1, i2; };

__device__ __forceinline__ void t2_init(Top2& t) {
    t.v1 = -INFINITY; t.v2 = -INFINITY; t.i1 = 0x7FFFFFFF; t.i2 = 0x7FFFFFFF;
}

__device__ __forceinline__ void t2_push(Top2& t, float v, int i) {
    if (better(v, i, t.v2, t.i2)) {
        if (better(v, i, t.v1, t.i1)) { t.v2 = t.v1; t.i2 = t.i1; t.v1 = v; t.i1 = i; }
        else                          { t.v2 = v;    t.i2 = i; }
    }
}

// merge sorted pair b into sorted pair a
__device__ __forceinline__ void t2_merge(Top2& a, const Top2& b) {
    if (better(b.v1, b.i1, a.v1, a.i1)) {
        float nv2; int ni2;
        if (better(a.v1, a.i1, b.v2, b.i2)) { nv2 = a.v1; ni2 = a.i1; }
        else                                { nv2 = b.v2; ni2 = b.i2; }
        a.v1 = b.v1; a.i1 = b.i1; a.v2 = nv2; a.i2 = ni2;
    } else {
        if (better(b.v1, b.i1, a.v2, a.i2)) { a.v2 = b.v1; a.i2 = b.i1; }
    }
}

__global__ __launch_bounds__(TPB) void dbs_kernel(
    const float* __restrict__ lprobs,   // (64,8,50257)
    const float* __restrict__ scores,   // (64,8,128)
    const float* __restrict__ overlap,  // (64,4,4)
    const int*   __restrict__ obi,      // (64,)
    const int*   __restrict__ lastn,    // (64,8,1)
    const int*   __restrict__ mask,     // (64,8,2)
    const int*   __restrict__ stepp,    // (1,)
    float*       __restrict__ out)      // 2560 floats
{
    const int b   = blockIdx.x;
    const int tid = threadIdx.x;
    const int wave = tid >> 6;
    const int lane = tid & 63;
    const int step = stepp[0];
    const int ob   = obi[b];

    __shared__ float s_sc[MB];
    __shared__ int   s_valid[MB];
    __shared__ float s_pen[(NG - 1) * KC];
    __shared__ int   s_penidx[(NG - 1) * KC];
    __shared__ int   s_np;
    __shared__ float s_selv[NG][KC];
    __shared__ int   s_seli[NG][KC];   // vocab index
    __shared__ int   s_selm[NG][KC];   // which m (beam slot within group)
    __shared__ float s_rv1[TPB / 64], s_rv2[TPB / 64];
    __shared__ int   s_ri1[TPB / 64], s_ri2[TPB / 64];

    for (int g = 0; g < NG; ++g) {
        if (tid < MB) {
            const int m    = tid;
            const int beam = m * NG + g;
            const int* mk  = mask + ((size_t)b * BEAM + beam) * NGRAM;
            s_valid[m] = (mk[0] + mk[1]) == NGRAM;
            s_sc[m]    = scores[((size_t)b * BEAM + beam) * TLEN + (step - 1)];
        }
        if (tid == 0) {
            int np = 0;
            for (int j = 0; j < g; ++j) {
                const float pen = 1.0f + overlap[((size_t)ob * NG + g) * NG + j];
                for (int m2 = 0; m2 < KC; ++m2) {
                    s_penidx[np] = s_seli[j][m2];
                    s_pen[np]    = pen;
                    ++np;
                }
            }
            s_np = np;
        }
        __syncthreads();

        Top2 t; t2_init(t);
        const int np = s_np;                // block-uniform
        for (int m = 0; m < MB; ++m) {
            if (!s_valid[m]) continue;      // block-uniform: invalid rows are analytic
            const float sc = s_sc[m];
            const float* row = lprobs + ((size_t)b * BEAM + (size_t)m * NG + g) * VOCAB;
            const int fbase = m * VOCAB;
            if (np == 0) {
                for (int v = tid; v < VOCAB; v += TPB) {
                    const float val = row[v] + sc;
                    t2_push(t, val, fbase + v);
                }
            } else {
                for (int v = tid; v < VOCAB; v += TPB) {
                    float lp = row[v];
                    float dv = 0.0f;
                    #pragma unroll
                    for (int p = 0; p < (NG - 1) * KC; ++p)
                        if (p < np && s_penidx[p] == v) dv += s_pen[p];
                    lp = lp + (-0.5f) * dv;   // DIVERSITY_STRENGTH = -0.5
                    const float val = lp + sc;
                    t2_push(t, val, fbase + v);
                }
            }
        }

        // intra-wave reduction (64 lanes)
        for (int off = 32; off > 0; off >>= 1) {
            Top2 o;
            o.v1 = __shfl_down(t.v1, off);
            o.i1 = __shfl_down(t.i1, off);
            o.v2 = __shfl_down(t.v2, off);
            o.i2 = __shfl_down(t.i2, off);
            t2_merge(t, o);
        }
        if (lane == 0) {
            s_rv1[wave] = t.v1; s_ri1[wave] = t.i1;
            s_rv2[wave] = t.v2; s_ri2[wave] = t.i2;
        }
        __syncthreads();
        if (tid == 0) {
            Top2 f; t2_init(f);
            for (int w = 0; w < TPB / 64; ++w) {
                Top2 o;
                o.v1 = s_rv1[w]; o.i1 = s_ri1[w];
                o.v2 = s_rv2[w]; o.i2 = s_ri2[w];
                t2_merge(f, o);
            }
            // invalid beams: all-vocab constant sc -> best two are flat idx m*VOCAB, m*VOCAB+1
            for (int m = 0; m < MB; ++m) {
                if (s_valid[m]) continue;
                Top2 o;
                o.v1 = s_sc[m]; o.i1 = m * VOCAB;
                o.v2 = s_sc[m]; o.i2 = m * VOCAB + 1;
                t2_merge(f, o);
            }
            s_selv[g][0] = f.v1; s_seli[g][0] = f.i1 % VOCAB; s_selm[g][0] = f.i1 / VOCAB;
            s_selv[g][1] = f.v2; s_seli[g][1] = f.i2 % VOCAB; s_selm[g][1] = f.i2 / VOCAB;
        }
        __syncthreads();
    }

    // ---- outputs ----
    // layout: scores[0,512) indices[512,1024) beams[1024,1536) overlap[1536,2560)
    if (tid < KC * NG) {            // 8 writers: i = m*NG + g
        const int i = tid;
        const int m = i / NG, g = i % NG;
        out[(size_t)b * BEAM + i]          = s_selv[g][m];
        out[512 + (size_t)b * BEAM + i]    = (float)s_seli[g][m];
        out[1024 + (size_t)b * BEAM + i]   = (float)(s_selm[g][m] * NG + g);
    }
    if (tid >= 64 && tid < 64 + NG * NG) {  // 16 writers on wave 1 (independent of wave 0 writes)
        const int q  = tid - 64;
        const int g1 = q / NG, g2 = q % NG;
        int ov = 0;
        for (int m = 0; m < MB; ++m) {
            const int i1 = m * NG + g1, i2 = m * NG + g2;
            const int p1a = lastn[(size_t)b * BEAM + i1];
            const int p2a = lastn[(size_t)b * BEAM + i2];
            const int p1b = s_seli[g1][m];
            const int p2b = s_seli[g2][m];
            const int* mk1 = mask + ((size_t)b * BEAM + i1) * NGRAM;
            const int* mk2 = mask + ((size_t)b * BEAM + i2) * NGRAM;
            const bool e0 = (p1a == p2a) && (mk1[0] != 0) && (mk2[0] != 0);
            const bool e1 = (p1b == p2b) && (mk1[1] != 0) && (mk2[1] != 0);
            ov += (e0 && e1) ? 1 : 0;
        }
        out[1536 + (size_t)ob * (NG * NG) + q] =
            (overlap[(size_t)ob * (NG * NG) + q] + (float)ov) * 0.5f;  // DIVERSITY_DISCOUNT
    }
}

extern "C" void kernel_launch(void* const* d_in, const int* in_sizes, int n_in,
                              void* d_out, int out_size, void* d_ws, size_t ws_size,
                              hipStream_t stream) {
    const float* lprobs  = (const float*)d_in[0];
    const float* scores  = (const float*)d_in[1];
    const float* overlap = (const float*)d_in[2];
    const int*   obi     = (const int*)d_in[3];
    const int*   lastn   = (const int*)d_in[4];
    const int*   mask    = (const int*)d_in[5];
    const int*   stepp   = (const int*)d_in[6];
    float*       out     = (float*)d_out;

    dbs_kernel<<<BSZ, TPB, 0, stream>>>(lprobs, scores, overlap, obi, lastn, mask, stepp, out);
}

// Round 2
// 106.826 us; speedup vs baseline: 1.0155x; 1.0155x over previous
//
#include <hip/hip_runtime.h>
#include <math.h>

#define VOCAB 50257
#define BSZ   64
#define BEAM  8
#define NG    4     // NUM_GROUPS
#define MB    2     // beams per group
#define KC    2     // candidates per group
#define TLEN  128
#define NGRAM 2
#define SEG   8
#define SEGLEN 6283              // ceil(VOCAB/SEG)
#define ROWS  (BSZ * BEAM)       // 512
#define EPR   (SEG * 8)          // ws entries per row = 64

__device__ __forceinline__ bool better(float v1, int i1, float v2, int i2) {
    return (v1 > v2) || (v1 == v2 && i1 < i2);
}

struct Top2 { float v1, v2; int i1, i2; };

__device__ __forceinline__ void t2_init(Top2& t) {
    t.v1 = -INFINITY; t.v2 = -INFINITY; t.i1 = 0x7FFFFFFF; t.i2 = 0x7FFFFFFF;
}

__device__ __forceinline__ void t2_push(Top2& t, float v, int i) {
    if (better(v, i, t.v2, t.i2)) {
        if (better(v, i, t.v1, t.i1)) { t.v2 = t.v1; t.i2 = t.i1; t.v1 = v; t.i1 = i; }
        else                          { t.v2 = v;    t.i2 = i; }
    }
}

__device__ __forceinline__ void t2_merge(Top2& a, const Top2& b) {
    if (better(b.v1, b.i1, a.v1, a.i1)) {
        float nv2; int ni2;
        if (better(a.v1, a.i1, b.v2, b.i2)) { nv2 = a.v1; ni2 = a.i1; }
        else                                { nv2 = b.v2; ni2 = b.i2; }
        a.v1 = b.v1; a.i1 = b.i1; a.v2 = nv2; a.i2 = ni2;
    } else {
        if (better(b.v1, b.i1, a.v2, a.i2)) { a.v2 = b.v1; a.i2 = b.i1; }
    }
}

// ---------------- Phase 1: per (row, segment) lex top-8 -> ws ----------------
__global__ __launch_bounds__(64) void dbs_phase1(
    const float* __restrict__ lprobs,   // (512, 50257)
    const int*   __restrict__ mask,     // (512, 2)
    float* __restrict__ wsv,            // (512*64)
    int*   __restrict__ wsi)            // (512*64)
{
    const int bid  = blockIdx.x;
    const int r    = bid >> 3;          // row = b*8 + beam
    const int seg  = bid & 7;
    const int lane = threadIdx.x;

    // invalid rows contribute analytically in phase 2 — skip all reads
    if (mask[r * NGRAM] + mask[r * NGRAM + 1] != NGRAM) return;

    const float* row = lprobs + (size_t)r * VOCAB;
    const int start = seg * SEGLEN;
    const int end   = min(start + SEGLEN, VOCAB);

    // per-thread sorted top-8 (descending lex), static-indexed only
    float tv[8]; int ti[8];
    #pragma unroll
    for (int j = 0; j < 8; ++j) { tv[j] = -INFINITY; ti[j] = 0x7FFFFFFF; }

    for (int v = start + lane; v < end; v += 64) {
        const float val = row[v];
        if (better(val, v, tv[7], ti[7])) {
            tv[7] = val; ti[7] = v;
            #pragma unroll
            for (int j = 7; j >= 1; --j) {
                if (better(tv[j], ti[j], tv[j-1], ti[j-1])) {
                    float fv = tv[j]; tv[j] = tv[j-1]; tv[j-1] = fv;
                    int   fi = ti[j]; ti[j] = ti[j-1]; ti[j-1] = fi;
                }
            }
        }
    }

    // 8 rounds: wave argmax of heads (xor butterfly), owner pops (shift left)
    const int base = r * EPR + seg * 8;
    #pragma unroll
    for (int round = 0; round < 8; ++round) {
        float mv = tv[0]; int mi = ti[0];
        #pragma unroll
        for (int off = 32; off > 0; off >>= 1) {
            const float ov = __shfl_xor(mv, off);
            const int   oi = __shfl_xor(mi, off);
            if (better(ov, oi, mv, mi)) { mv = ov; mi = oi; }
        }
        if (lane == 0) { wsv[base + round] = mv; wsi[base + round] = mi; }
        if (tv[0] == mv && ti[0] == mi) {        // unique owner (indices distinct)
            #pragma unroll
            for (int j = 0; j < 7; ++j) { tv[j] = tv[j+1]; ti[j] = ti[j+1]; }
            tv[7] = -INFINITY; ti[7] = 0x7FFFFFFF;
        }
    }
}

// ---------------- Phase 2: per-batch sequential group chain on candidates ----
__global__ __launch_bounds__(64) void dbs_phase2(
    const float* __restrict__ scores,   // (64,8,128)
    const float* __restrict__ overlap,  // (64,4,4)
    const int*   __restrict__ obi,      // (64,)
    const int*   __restrict__ lastn,    // (64,8,1)
    const int*   __restrict__ mask,     // (64,8,2)
    const int*   __restrict__ stepp,    // (1,)
    const float* __restrict__ wsv,
    const int*   __restrict__ wsi,
    float*       __restrict__ out)      // 2560 floats
{
    const int b   = blockIdx.x;
    const int tid = threadIdx.x;
    const int step = stepp[0];
    const int ob   = obi[b];

    __shared__ float s_sc[BEAM];
    __shared__ int   s_valid[BEAM];
    __shared__ float s_pen[(NG-1)*KC];
    __shared__ int   s_penidx[(NG-1)*KC];
    __shared__ float s_selv[NG][KC];
    __shared__ int   s_seli[NG][KC];
    __shared__ int   s_selm[NG][KC];

    if (tid < BEAM) {
        const int* mk = mask + ((size_t)b * BEAM + tid) * NGRAM;
        s_valid[tid] = (mk[0] + mk[1]) == NGRAM;
        s_sc[tid]    = scores[((size_t)b * BEAM + tid) * TLEN + (step - 1)];
    }
    __syncthreads();

    for (int g = 0; g < NG; ++g) {
        if (tid == 0) {
            for (int j = 0; j < g; ++j) {
                const float pen = 1.0f + overlap[((size_t)ob * NG + g) * NG + j];
                s_penidx[j*KC + 0] = s_seli[j][0]; s_pen[j*KC + 0] = pen;
                s_penidx[j*KC + 1] = s_seli[j][1]; s_pen[j*KC + 1] = pen;
            }
        }
        __syncthreads();

        const int np = KC * g;            // block-uniform
        Top2 t; t2_init(t);
        for (int m = 0; m < MB; ++m) {
            const int beam = m * NG + g;
            if (s_valid[beam]) {          // block-uniform branch
                const int r = b * BEAM + beam;
                const float v  = wsv[r * EPR + tid];
                const int   idx = wsi[r * EPR + tid];
                float dv = 0.0f;
                #pragma unroll
                for (int p = 0; p < (NG-1)*KC; ++p)
                    if (p < np && s_penidx[p] == idx) dv += s_pen[p];
                t2_push(t, v - 0.5f * dv + s_sc[beam], m * VOCAB + idx);
            } else if (tid < KC) {
                // invalid row: constant sc -> best two flat idx m*V, m*V+1
                t2_push(t, s_sc[beam], m * VOCAB + tid);
            }
        }

        for (int off = 32; off > 0; off >>= 1) {
            Top2 o;
            o.v1 = __shfl_down(t.v1, off); o.i1 = __shfl_down(t.i1, off);
            o.v2 = __shfl_down(t.v2, off); o.i2 = __shfl_down(t.i2, off);
            t2_merge(t, o);
        }
        if (tid == 0) {
            s_selv[g][0] = t.v1; s_seli[g][0] = t.i1 % VOCAB; s_selm[g][0] = t.i1 / VOCAB;
            s_selv[g][1] = t.v2; s_seli[g][1] = t.i2 % VOCAB; s_selm[g][1] = t.i2 / VOCAB;
        }
        __syncthreads();
    }

    // ---- outputs: scores[0,512) indices[512,1024) beams[1024,1536) overlap[1536,2560)
    if (tid < KC * NG) {                  // i = m*NG + g
        const int i = tid;
        const int m = i / NG, g = i % NG;
        out[(size_t)b * BEAM + i]        = s_selv[g][m];
        out[512 + (size_t)b * BEAM + i]  = (float)s_seli[g][m];
        out[1024 + (size_t)b * BEAM + i] = (float)(s_selm[g][m] * NG + g);
    }
    if (tid >= 16 && tid < 16 + NG * NG) {
        const int q  = tid - 16;
        const int g1 = q / NG, g2 = q % NG;
        int ov = 0;
        for (int m = 0; m < MB; ++m) {
            const int i1 = m * NG + g1, i2 = m * NG + g2;
            const int p1a = lastn[(size_t)b * BEAM + i1];
            const int p2a = lastn[(size_t)b * BEAM + i2];
            const int p1b = s_seli[g1][m];
            const int p2b = s_seli[g2][m];
            const int* mk1 = mask + ((size_t)b * BEAM + i1) * NGRAM;
            const int* mk2 = mask + ((size_t)b * BEAM + i2) * NGRAM;
            const bool e0 = (p1a == p2a) && (mk1[0] != 0) && (mk2[0] != 0);
            const bool e1 = (p1b == p2b) && (mk1[1] != 0) && (mk2[1] != 0);
            ov += (e0 && e1) ? 1 : 0;
        }
        out[1536 + (size_t)ob * (NG * NG) + q] =
            (overlap[(size_t)ob * (NG * NG) + q] + (float)ov) * 0.5f;
    }
}

extern "C" void kernel_launch(void* const* d_in, const int* in_sizes, int n_in,
                              void* d_out, int out_size, void* d_ws, size_t ws_size,
                              hipStream_t stream) {
    const float* lprobs  = (const float*)d_in[0];
    const float* scores  = (const float*)d_in[1];
    const float* overlap = (const float*)d_in[2];
    const int*   obi     = (const int*)d_in[3];
    const int*   lastn   = (const int*)d_in[4];
    const int*   mask    = (const int*)d_in[5];
    const int*   stepp   = (const int*)d_in[6];
    float*       out     = (float*)d_out;

    float* wsv = (float*)d_ws;
    int*   wsi = (int*)((char*)d_ws + (size_t)ROWS * EPR * sizeof(float));

    dbs_phase1<<<ROWS * SEG, 64, 0, stream>>>(lprobs, mask, wsv, wsi);
    dbs_phase2<<<BSZ, 64, 0, stream>>>(scores, overlap, obi, lastn, mask, stepp,
                                       wsv, wsi, out);
}